// Round 8
// baseline (245.276 us; speedup 1.0000x reference)
//
#include <hip/hip_runtime.h>
#include <hip/hip_bf16.h>

#define N_NODES 20000
#define N_EDGES 320000
#define BN_EPS  1e-5f

#define CNTB     313                        // ceil(320000/1024) count blocks
#define CVTB     512                        // cvt blocks (1024 thr each)
#define GEMM_MT  ((N_NODES + 127) / 128)    // 157
#define NGEMM    640                        // 8 XCD * 20 tiles * 4 by (12 guarded idle)
#define FILLB    625                        // 625*256*2 = 320000: 2 edges/thread

typedef __attribute__((ext_vector_type(4))) float f32x4;
typedef __attribute__((ext_vector_type(8))) __bf16 bf16x8;
typedef __attribute__((ext_vector_type(4))) unsigned short u16x4;

__device__ __forceinline__ unsigned short f2bf(float f) {   // RNE f32->bf16
    unsigned int u = __float_as_uint(f);
    u += 0x7fffu + ((u >> 16) & 1u);
    return (unsigned short)(u >> 16);
}
__device__ __forceinline__ float bflo(unsigned int u) { return __uint_as_float(u << 16); }
__device__ __forceinline__ float bfhi(unsigned int u) { return __uint_as_float(u & 0xffff0000u); }

__device__ __forceinline__ void gload_lds16(const void* g, void* l) {
    __builtin_amdgcn_global_load_lds(
        (const __attribute__((address_space(1))) void*)g,
        (__attribute__((address_space(3))) void*)l, 16, 0, 0);
}

// ---------------------------------------------------------------------------
// zero: cntF, cntB, done, stats (162 KB). Must strictly precede count atomics,
// hence its own tiny dispatch (blocks within one kernel have no ordering).
// ---------------------------------------------------------------------------
__global__ void zero_kernel(uint4* __restrict__ zp, int n) {
    int i = blockIdx.x * blockDim.x + threadIdx.x;
    if (i < n) zp[i] = make_uint4(0u, 0u, 0u, 0u);
}

// ---------------------------------------------------------------------------
// Merged cvt + count_rank + scan (one dispatch, 1024-thr blocks):
//  - blocks [0,CNTB): per-edge count atomics, rank capture (atomicAdd return
//    IS the within-node rank; makes the later fill atomic-free), then the
//    LAST block to finish (done-counter) runs both exclusive scans itself.
//    cnt atomics live at the device coherence point; this block never cached
//    cnt lines, so its plain loads see final values. No spin-waits.
//  - blocks [CNTB,..): grid-stride bf16 conversion of x and the 4 W mats.
//    Count's atomic latency hides under this streaming work.
// ---------------------------------------------------------------------------
#define SCAN_PER 20
__global__ __launch_bounds__(1024) void cvt_count_scan_kernel(
    const float* __restrict__ x,
    const float* __restrict__ Wlf, const float* __restrict__ Wlb,
    const float* __restrict__ Wrf, const float* __restrict__ Wrb,
    unsigned short* __restrict__ Xb, unsigned short* __restrict__ Wb,
    const int* __restrict__ src, const int* __restrict__ dst,
    int* __restrict__ cntF, int* __restrict__ cntB,
    unsigned int* __restrict__ rank2,
    int* __restrict__ offF, int* __restrict__ offB,
    int* __restrict__ done)
{
    int tid = threadIdx.x;

    if (blockIdx.x < CNTB) {
        __shared__ int sh[1024];
        __shared__ int amLast;
        int e = blockIdx.x * 1024 + tid;
        if (e < N_EDGES) {
            unsigned int p = (unsigned int)atomicAdd(&cntF[dst[e]], 1);
            unsigned int q = (unsigned int)atomicAdd(&cntB[src[e]], 1);
            rank2[e] = p | (q << 16);
        }
        __syncthreads();
        if (tid == 0) {
            __threadfence();                       // release our cnt atomics
            int old = atomicAdd(done, 1);
            amLast = (old == CNTB - 1);
        }
        __syncthreads();
        if (!amLast) return;
        __threadfence();                           // acquire others' atomics

        // last block: exclusive scan of both count arrays
        for (int pass = 0; pass < 2; ++pass) {
            const int* in  = pass ? cntB : cntF;
            int*       out = pass ? offB : offF;
            int base = tid * SCAN_PER;
            int v[SCAN_PER];
            int sum = 0;
            #pragma unroll
            for (int k = 0; k < SCAN_PER; ++k) {
                int i = base + k;
                int c = (i < N_NODES) ? in[i] : 0;
                v[k] = sum; sum += c;
            }
            sh[tid] = sum;
            __syncthreads();
            for (int o = 1; o < 1024; o <<= 1) {
                int xv = (tid >= o) ? sh[tid - o] : 0;
                __syncthreads();
                sh[tid] += xv;
                __syncthreads();
            }
            int pre = tid ? sh[tid - 1] : 0;
            #pragma unroll
            for (int k = 0; k < SCAN_PER; ++k) {
                int i = base + k;
                if (i < N_NODES) out[i] = pre + v[k];
            }
            if (tid == 1023) out[N_NODES] = sh[1023];
            __syncthreads();                       // sh reused next pass
        }
        return;
    }

    // ---- cvt part ----
    const int XQ = N_NODES * 256 / 4;         // 1,280,000
    const int WQ = 128 * 256 / 4;             // 8,192 per matrix
    const int total = XQ + 4 * WQ;
    for (int i = (blockIdx.x - CNTB) * 1024 + tid; i < total; i += CVTB * 1024) {
        const float* sp;
        unsigned short* dp;
        if (i < XQ) {
            sp = x + (size_t)i * 4;
            dp = Xb + (size_t)i * 4;
        } else {
            int w = i - XQ;
            int mat = w / WQ;
            int o = (w - mat * WQ) * 4;
            if      (mat == 0) sp = Wlf + o;
            else if (mat == 1) sp = Wlb + o;
            else if (mat == 2) sp = Wrf + o;
            else               sp = Wrb + o;
            dp = Wb + (size_t)mat * 32768 + o;
        }
        float4 v = *(const float4*)sp;
        u16x4 r = {f2bf(v.x), f2bf(v.y), f2bf(v.z), f2bf(v.w)};
        *(u16x4*)dp = r;
    }
}

// ---------------------------------------------------------------------------
// Merged GEMM + fill. GEMM blocks first; XCD-aware mapping so the 4 blocks
// sharing one Xb tile land on the SAME XCD's L2 (consecutive blockIdx
// round-robins across the 8 XCDs): xcd=gb&7, by=(gb>>3)&3, mTile=(gb>>5)+20*xcd.
// Fill blocks trail and are atomic-free (rank2 precomputed): 2 independent
// scattered stores per edge, overlapping under the GEMM.
// GEMM: double-buffered BK=64 with counted vmcnt:
//   STAGE(t+1) -> s_waitcnt vmcnt(8) -> s_barrier -> MFMA(t) -> s_barrier
// XOR-swizzled staging (pre-swizzled source + swizzled ds_read; rule #21).
// ---------------------------------------------------------------------------
__global__ __launch_bounds__(256) void gemm_fill_kernel(
    const int* __restrict__ src, const int* __restrict__ dst,
    const int* __restrict__ offF, const int* __restrict__ offB,
    const unsigned int* __restrict__ rank2,
    int* __restrict__ listF, int* __restrict__ listB,
    const unsigned short* __restrict__ Xb, const unsigned short* __restrict__ Wb,
    unsigned short* __restrict__ Y, float* __restrict__ Z)
{
    __shared__ unsigned short As[2][128 * 64];   // 2 x 16 KB
    __shared__ unsigned short Bs[2][128 * 64];   // 2 x 16 KB

    if (blockIdx.x >= NGEMM) {
        // CSR fill: no atomics, pure scattered stores (rank precomputed)
        int t = (blockIdx.x - NGEMM) * 256 + threadIdx.x;   // 0..159999
        #pragma unroll
        for (int h = 0; h < 2; ++h) {
            int e = t + h * (N_EDGES / 2);
            int s = src[e], d = dst[e];
            unsigned int r2 = rank2[e];
            listF[offF[d] + (int)(r2 & 0xffffu)] = s;
            listB[offB[s] + (int)(r2 >> 16)] = d;
        }
        return;
    }

    int gb = blockIdx.x;
    int xcd = gb & 7;
    int by = (gb >> 3) & 3;
    int mTile = (gb >> 5) + 20 * xcd;
    if (mTile >= GEMM_MT) return;
    int mBase = mTile * 128;
    int tid = threadIdx.x, lane = tid & 63, wave = tid >> 6;
    int wr = wave >> 1, wc = wave & 1;
    const unsigned short* W = Wb + (size_t)by * 128 * 256;

    f32x4 acc[4][4] = {};

    auto STAGE = [&](int b, int k0) {
        #pragma unroll
        for (int c = 0; c < 4; ++c) {
            int S = c * 256 + tid;                 // 16B slot index, 0..1023
            int row = S >> 3;
            int q = (S & 7) ^ (row & 7);           // pre-swizzled source slot
            int gm = mBase + row; gm = gm < N_NODES ? gm : N_NODES - 1;
            gload_lds16(Xb + (size_t)gm * 256 + k0 + q * 8, &As[b][S * 8]);
            gload_lds16(W + (size_t)row * 256 + k0 + q * 8, &Bs[b][S * 8]);
        }
    };
    auto COMPUTE = [&](int b) {
        #pragma unroll
        for (int ks = 0; ks < 2; ++ks) {
            bf16x8 af[4], bfr[4];
            int sl = ks * 4 + (lane >> 4);
            #pragma unroll
            for (int m = 0; m < 4; ++m) {
                int row = wr * 64 + m * 16 + (lane & 15);
                af[m] = *(const bf16x8*)&As[b][row * 64 + ((sl ^ (row & 7)) * 8)];
            }
            #pragma unroll
            for (int n = 0; n < 4; ++n) {
                int row = wc * 64 + n * 16 + (lane & 15);
                bfr[n] = *(const bf16x8*)&Bs[b][row * 64 + ((sl ^ (row & 7)) * 8)];
            }
            #pragma unroll
            for (int m = 0; m < 4; ++m)
                #pragma unroll
                for (int n = 0; n < 4; ++n)
                    acc[m][n] = __builtin_amdgcn_mfma_f32_16x16x32_bf16(af[m], bfr[n], acc[m][n], 0, 0, 0);
        }
    };

    STAGE(0, 0);                                   // prologue: tile 0 in flight
    #pragma unroll
    for (int t = 0; t < 4; ++t) {
        if (t < 3) {
            STAGE((t + 1) & 1, (t + 1) * 64);      // tile t+1 in flight (8 loads)
            asm volatile("s_waitcnt vmcnt(8)" ::: "memory");   // tile t done
        } else {
            asm volatile("s_waitcnt vmcnt(0)" ::: "memory");
        }
        __builtin_amdgcn_s_barrier();              // all waves: tile t ready
        __builtin_amdgcn_sched_barrier(0);
        COMPUTE(t & 1);
        __builtin_amdgcn_s_barrier();              // done reading buf before overwrite
    }

    bool toY = by < 2;
    int cBase = (by & 1) * 128 + wc * 64;
    #pragma unroll
    for (int m = 0; m < 4; ++m) {
        int gm0 = mBase + wr * 64 + m * 16 + (lane >> 4) * 4;
        #pragma unroll
        for (int n = 0; n < 4; ++n) {
            int gn = cBase + n * 16 + (lane & 15);
            f32x4 v = acc[m][n];
            #pragma unroll
            for (int j = 0; j < 4; ++j) {
                int gm = gm0 + j;
                if (gm < N_NODES) {
                    if (toY) Y[(size_t)gm * 256 + gn] = f2bf(v[j]);
                    else     Z[(size_t)gm * 256 + gn] = v[j];
                }
            }
        }
    }
}

// ---------------------------------------------------------------------------
// Aggregation + BN stats: wave = one (node,dir) stream, NPW=4 nodes/wave.
// 16 lanes cover one 128-col bf16 half-row (16B/lane): one wave-load gathers
// 4 edges; 4 loads in flight, plus all NPW first list-chunks prefetched up
// front. __shfl executes UNCONDITIONALLY (ds_bpermute reads 0 from
// exec-inactive source lanes); only the load is predicated.
// BN partials per-thread (each lane owns 2 fixed columns) -> LDS pair-reduce
// across half-waves -> 512 atomics/block (removes the bn_stats pass).
// ---------------------------------------------------------------------------
#define NPW 4
__global__ __launch_bounds__(256) void aggregate_stats_kernel(
    const unsigned short* __restrict__ Y,
    const int* __restrict__ offF, const int* __restrict__ listF,
    const int* __restrict__ offB, const int* __restrict__ listB,
    float* __restrict__ H, float* __restrict__ stats)
{
    int tid = threadIdx.x, lane = tid & 63, wave = tid >> 6;
    int dir = wave >> 1, half = wave & 1;
    const int* off  = dir ? offB : offF;
    const int* list = dir ? listB : listF;
    int eg = lane >> 4;        // which edge of the group of 4
    int c16 = lane & 15;       // 16B column slot within the row
    int nodeBase = blockIdx.x * (2 * NPW) + half * NPW;

    // prefetch: offsets + first 64-edge chunk of every node (NPW loads in flight)
    int begs[NPW], degs[NPW], ul0[NPW];
    #pragma unroll
    for (int jn = 0; jn < NPW; ++jn) {
        int n = nodeBase + jn;
        int b = off[n], e = off[n + 1];
        begs[jn] = b; degs[jn] = e - b;
        int c = e - b; if (c > 64) c = 64;
        ul0[jn] = list[b + (lane < c ? lane : 0)];
    }

    float s1a = 0.f, s1b = 0.f, s2a = 0.f, s2b = 0.f;

    #pragma unroll
    for (int jn = 0; jn < NPW; ++jn) {
        int n = nodeBase + jn;
        int deg = degs[jn];
        float acc[8] = {0.f, 0.f, 0.f, 0.f, 0.f, 0.f, 0.f, 0.f};

        auto process = [&](int u_l, int c) {
            for (int e0 = 0; e0 < c; e0 += 16) {
                uint4 v[4];
                #pragma unroll
                for (int k = 0; k < 4; ++k) {
                    int ei = e0 + k * 4 + eg;
                    int u = __shfl(u_l, ei < c ? ei : 0);   // all lanes active
                    v[k] = make_uint4(0u, 0u, 0u, 0u);
                    if (ei < c)
                        v[k] = *(const uint4*)(Y + (size_t)u * 256 + dir * 128 + c16 * 8);
                }
                #pragma unroll
                for (int k = 0; k < 4; ++k) {
                    acc[0] += bflo(v[k].x); acc[1] += bfhi(v[k].x);
                    acc[2] += bflo(v[k].y); acc[3] += bfhi(v[k].y);
                    acc[4] += bflo(v[k].z); acc[5] += bfhi(v[k].z);
                    acc[6] += bflo(v[k].w); acc[7] += bfhi(v[k].w);
                }
            }
        };

        process(ul0[jn], deg < 64 ? deg : 64);
        for (int i = begs[jn] + 64; i < begs[jn] + deg; i += 64) {   // rare deg>64
            int c = begs[jn] + deg - i; if (c > 64) c = 64;
            int u_l = list[i + (lane < c ? lane : 0)];
            process(u_l, c);
        }

        #pragma unroll
        for (int j = 0; j < 8; ++j) {
            acc[j] += __shfl_xor(acc[j], 16);
            acc[j] += __shfl_xor(acc[j], 32);
        }
        // static-index select of this lane's two columns (rule #20)
        float h0 = (eg & 2) ? ((eg & 1) ? acc[6] : acc[4]) : ((eg & 1) ? acc[2] : acc[0]);
        float h1 = (eg & 2) ? ((eg & 1) ? acc[7] : acc[5]) : ((eg & 1) ? acc[3] : acc[1]);
        float inv = 1.f / fmaxf((float)deg, 1.f);
        float2* hp = (float2*)(H + (size_t)n * 256 + dir * 128 + c16 * 8 + eg * 2);
        float2 z = *hp;
        float v0 = fmaf(h0, inv, z.x);
        float v1 = fmaf(h1, inv, z.y);
        *hp = make_float2(v0, v1);
        s1a += v0; s2a += v0 * v0;
        s1b += v1; s2b += v1 * v1;
    }

    // BN partials: pair-reduce across the two half-waves of each dir, then
    // 4 atomics per lane of the half0 waves (512 atomics/block total).
    __shared__ float red[2][64][4];
    if (half) {
        red[dir][lane][0] = s1a; red[dir][lane][1] = s1b;
        red[dir][lane][2] = s2a; red[dir][lane][3] = s2b;
    }
    __syncthreads();
    if (!half) {
        s1a += red[dir][lane][0]; s1b += red[dir][lane][1];
        s2a += red[dir][lane][2]; s2b += red[dir][lane][3];
        int col = dir * 128 + c16 * 8 + eg * 2;
        atomicAdd(&stats[col], s1a);
        atomicAdd(&stats[col + 1], s1b);
        atomicAdd(&stats[256 + col], s2a);
        atomicAdd(&stats[256 + col + 1], s2b);
    }
}

// ---------------------------------------------------------------------------
// BatchNorm finalize + ReLU, in place on d_out.
// ---------------------------------------------------------------------------
__global__ __launch_bounds__(256) void bn_kernel(
    const float* __restrict__ stats, const float* __restrict__ gamma,
    const float* __restrict__ beta, float* __restrict__ H)
{
    __shared__ float sc[256], sf[256];
    int tid = threadIdx.x;
    {
        float mean = stats[tid] * (1.f / N_NODES);
        float var  = stats[256 + tid] * (1.f / N_NODES) - mean * mean;
        float s = rsqrtf(fmaxf(var, 0.f) + BN_EPS) * gamma[tid];
        sc[tid] = s;
        sf[tid] = beta[tid] - mean * s;
    }
    __syncthreads();
    for (int n = blockIdx.x; n < N_NODES; n += gridDim.x) {
        size_t idx = (size_t)n * 256 + tid;
        float h = H[idx];
        H[idx] = fmaxf(h * sc[tid] + sf[tid], 0.f);
    }
}

// ---------------------------------------------------------------------------
extern "C" void kernel_launch(void* const* d_in, const int* in_sizes, int n_in,
                              void* d_out, int out_size, void* d_ws, size_t ws_size,
                              hipStream_t stream) {
    const float* x     = (const float*)d_in[0];
    const int*   edge  = (const int*)d_in[1];   // [2][N_EDGES]
    const float* Wlf   = (const float*)d_in[2];
    // d_in[3] = b_l_f : cancels under BatchNorm (per-column shift) - unused
    const float* Wrf   = (const float*)d_in[4];
    const float* Wlb   = (const float*)d_in[5];
    // d_in[6] = b_l_b : unused (cancels)
    const float* Wrb   = (const float*)d_in[7];
    const float* gamma = (const float*)d_in[8];
    const float* beta  = (const float*)d_in[9];
    float* out = (float*)d_out;

    const int* src = edge;
    const int* dst = edge + N_EDGES;

    char* ws = (char*)d_ws;
    size_t off = 0;
    auto alloc = [&](size_t bytes) { size_t r = off; off += (bytes + 255) & ~(size_t)255; return r; };
    unsigned short* Y  = (unsigned short*)(ws + alloc((size_t)N_NODES * 256 * 2)); // 10.24 MB
    unsigned short* Xb = (unsigned short*)(ws + alloc((size_t)N_NODES * 256 * 2)); // 10.24 MB
    unsigned short* Wb = (unsigned short*)(ws + alloc((size_t)4 * 128 * 256 * 2)); // 256 KB
    int* offF  = (int*)(ws + alloc((size_t)(N_NODES + 1) * 4));
    int* offB  = (int*)(ws + alloc((size_t)(N_NODES + 1) * 4));
    int* listF = (int*)(ws + alloc((size_t)N_EDGES * 4));
    int* listB = (int*)(ws + alloc((size_t)N_EDGES * 4));
    unsigned int* rank2 = (unsigned int*)(ws + alloc((size_t)N_EDGES * 4));        // 1.28 MB
    size_t zbase_off = off;
    int* cntF = (int*)(ws + alloc((size_t)N_NODES * 4));
    int* cntB = (int*)(ws + alloc((size_t)N_NODES * 4));
    int* done = (int*)(ws + alloc(256));
    float* stats = (float*)(ws + alloc(512 * 4));
    size_t zbytes = off - zbase_off;          // 256B-aligned => multiple of 16
    int zquads = (int)(zbytes / 16);

    zero_kernel<<<(zquads + 255) / 256, 256, 0, stream>>>((uint4*)(ws + zbase_off), zquads);

    cvt_count_scan_kernel<<<CNTB + CVTB, 1024, 0, stream>>>(
        x, Wlf, Wlb, Wrf, Wrb, Xb, Wb, src, dst, cntF, cntB, rank2, offF, offB, done);

    gemm_fill_kernel<<<NGEMM + FILLB, 256, 0, stream>>>(
        src, dst, offF, offB, rank2, listF, listB, Xb, Wb, Y, out);

    aggregate_stats_kernel<<<N_NODES / (2 * NPW), 256, 0, stream>>>(
        Y, offF, listF, offB, listB, out, stats);

    bn_kernel<<<2048, 256, 0, stream>>>(stats, gamma, beta, out);
}

// Round 9
// 132.418 us; speedup vs baseline: 1.8523x; 1.8523x over previous
//
#include <hip/hip_runtime.h>
#include <hip/hip_bf16.h>

#define N_NODES 20000
#define N_EDGES 320000
#define BN_EPS  1e-5f

#define CVTB2    2048                       // cvt blocks (FIRST: streaming fills CUs)
#define CNT256   1250                       // count blocks (trail; atomics hide under cvt)
#define GEMM_MT  ((N_NODES + 127) / 128)    // 157
#define NGEMM    (GEMM_MT * 4)              // 628 GEMM blocks (first)
#define FILLB    625                        // 625*256*2 = 320000: 2 edges/thread
#define NSTATS   8                          // stats copies (cap atomic chains at 625)

typedef __attribute__((ext_vector_type(4))) float f32x4;
typedef __attribute__((ext_vector_type(8))) __bf16 bf16x8;
typedef __attribute__((ext_vector_type(4))) unsigned short u16x4;

__device__ __forceinline__ unsigned short f2bf(float f) {   // RNE f32->bf16
    unsigned int u = __float_as_uint(f);
    u += 0x7fffu + ((u >> 16) & 1u);
    return (unsigned short)(u >> 16);
}
__device__ __forceinline__ float bflo(unsigned int u) { return __uint_as_float(u << 16); }
__device__ __forceinline__ float bfhi(unsigned int u) { return __uint_as_float(u & 0xffff0000u); }

__device__ __forceinline__ void gload_lds16(const void* g, void* l) {
    __builtin_amdgcn_global_load_lds(
        (const __attribute__((address_space(1))) void*)g,
        (__attribute__((address_space(3))) void*)l, 16, 0, 0);
}

// ---------------------------------------------------------------------------
// zero: cntF, cntB, stats copies (~176 KB). Must strictly precede the count
// atomics (no intra-kernel block ordering), hence its own tiny dispatch.
// ---------------------------------------------------------------------------
__global__ void zero_kernel(uint4* __restrict__ zp, int n) {
    int i = blockIdx.x * blockDim.x + threadIdx.x;
    if (i < n) zp[i] = make_uint4(0u, 0u, 0u, 0u);
}

// ---------------------------------------------------------------------------
// Merged cvt + count_rank (block-range split, cvt FIRST — R6 lesson: put the
// streaming work at low blockIdx so it saturates CUs while the latency-bound
// atomic work trickles behind).
//  - blocks [0,CVTB2): grid-stride bf16 convert of x and the 4 W mats.
//  - blocks [CVTB2,..): per-edge count atomics + rank capture (the atomicAdd
//    return IS the edge's within-node rank -> later fill is atomic-free).
// ---------------------------------------------------------------------------
__global__ __launch_bounds__(256) void cvt_count_kernel(
    const float* __restrict__ x,
    const float* __restrict__ Wlf, const float* __restrict__ Wlb,
    const float* __restrict__ Wrf, const float* __restrict__ Wrb,
    unsigned short* __restrict__ Xb, unsigned short* __restrict__ Wb,
    const int* __restrict__ src, const int* __restrict__ dst,
    int* __restrict__ cntF, int* __restrict__ cntB,
    unsigned int* __restrict__ rank2)
{
    int tid = threadIdx.x;
    if (blockIdx.x < CVTB2) {
        const int XQ = N_NODES * 256 / 4;         // 1,280,000
        const int WQ = 128 * 256 / 4;             // 8,192 per matrix
        const int total = XQ + 4 * WQ;
        for (int i = blockIdx.x * 256 + tid; i < total; i += CVTB2 * 256) {
            const float* sp;
            unsigned short* dp;
            if (i < XQ) {
                sp = x + (size_t)i * 4;
                dp = Xb + (size_t)i * 4;
            } else {
                int w = i - XQ;
                int mat = w / WQ;
                int o = (w - mat * WQ) * 4;
                if      (mat == 0) sp = Wlf + o;
                else if (mat == 1) sp = Wlb + o;
                else if (mat == 2) sp = Wrf + o;
                else               sp = Wrb + o;
                dp = Wb + (size_t)mat * 32768 + o;
            }
            float4 v = *(const float4*)sp;
            u16x4 r = {f2bf(v.x), f2bf(v.y), f2bf(v.z), f2bf(v.w)};
            *(u16x4*)dp = r;
        }
        return;
    }
    int e = (blockIdx.x - CVTB2) * 256 + tid;
    if (e < N_EDGES) {
        unsigned int p = (unsigned int)atomicAdd(&cntF[dst[e]], 1);
        unsigned int q = (unsigned int)atomicAdd(&cntB[src[e]], 1);
        rank2[e] = p | (q << 16);
    }
}

// ---------------------------------------------------------------------------
// Exclusive scan of both count arrays (2 blocks, one per direction).
// ---------------------------------------------------------------------------
#define SCAN_PER 20
__global__ __launch_bounds__(1024) void scan_kernel(const int* __restrict__ cntF, int* __restrict__ offF,
                                                    const int* __restrict__ cntB, int* __restrict__ offB) {
    const int* in  = blockIdx.x ? cntB : cntF;
    int*       out = blockIdx.x ? offB : offF;
    int t = threadIdx.x;
    int base = t * SCAN_PER;
    int v[SCAN_PER];
    int sum = 0;
    #pragma unroll
    for (int k = 0; k < SCAN_PER; ++k) {
        int i = base + k;
        int c = (i < N_NODES) ? in[i] : 0;
        v[k] = sum; sum += c;
    }
    __shared__ int sh[1024];
    sh[t] = sum;
    __syncthreads();
    for (int o = 1; o < 1024; o <<= 1) {
        int x = (t >= o) ? sh[t - o] : 0;
        __syncthreads();
        sh[t] += x;
        __syncthreads();
    }
    int pre = t ? sh[t - 1] : 0;
    #pragma unroll
    for (int k = 0; k < SCAN_PER; ++k) {
        int i = base + k;
        if (i < N_NODES) out[i] = pre + v[k];
    }
    if (t == 1023) out[N_NODES] = sh[1023];
}

// ---------------------------------------------------------------------------
// Merged GEMM + fill (exact round-7 structure). GEMM blocks first; fill
// blocks trail, atomic-free (rank2 precomputed): 2 independent scattered
// stores per edge, overlapping under the GEMM.
// GEMM: double-buffered BK=64 with counted vmcnt:
//   STAGE(t+1) -> s_waitcnt vmcnt(8) -> s_barrier -> MFMA(t) -> s_barrier
// XOR-swizzled staging (pre-swizzled source + swizzled ds_read; rule #21).
// ---------------------------------------------------------------------------
__global__ __launch_bounds__(256) void gemm_fill_kernel(
    const int* __restrict__ src, const int* __restrict__ dst,
    const int* __restrict__ offF, const int* __restrict__ offB,
    const unsigned int* __restrict__ rank2,
    int* __restrict__ listF, int* __restrict__ listB,
    const unsigned short* __restrict__ Xb, const unsigned short* __restrict__ Wb,
    unsigned short* __restrict__ Y, float* __restrict__ Z)
{
    __shared__ unsigned short As[2][128 * 64];   // 2 x 16 KB
    __shared__ unsigned short Bs[2][128 * 64];   // 2 x 16 KB

    if (blockIdx.x >= NGEMM) {
        // CSR fill: no atomics, pure scattered stores (rank precomputed)
        int t = (blockIdx.x - NGEMM) * 256 + threadIdx.x;   // 0..159999
        #pragma unroll
        for (int h = 0; h < 2; ++h) {
            int e = t + h * (N_EDGES / 2);
            int s = src[e], d = dst[e];
            unsigned int r2 = rank2[e];
            listF[offF[d] + (int)(r2 & 0xffffu)] = s;
            listB[offB[s] + (int)(r2 >> 16)] = d;
        }
        return;
    }

    int gb = blockIdx.x;
    int by = gb & 3;                 // 4 consecutive blocks share one Xb tile
    int mBase = (gb >> 2) * 128;
    int tid = threadIdx.x, lane = tid & 63, wave = tid >> 6;
    int wr = wave >> 1, wc = wave & 1;
    const unsigned short* W = Wb + (size_t)by * 128 * 256;

    f32x4 acc[4][4] = {};

    auto STAGE = [&](int b, int k0) {
        #pragma unroll
        for (int c = 0; c < 4; ++c) {
            int S = c * 256 + tid;                 // 16B slot index, 0..1023
            int row = S >> 3;
            int q = (S & 7) ^ (row & 7);           // pre-swizzled source slot
            int gm = mBase + row; gm = gm < N_NODES ? gm : N_NODES - 1;
            gload_lds16(Xb + (size_t)gm * 256 + k0 + q * 8, &As[b][S * 8]);
            gload_lds16(W + (size_t)row * 256 + k0 + q * 8, &Bs[b][S * 8]);
        }
    };
    auto COMPUTE = [&](int b) {
        #pragma unroll
        for (int ks = 0; ks < 2; ++ks) {
            bf16x8 af[4], bfr[4];
            int sl = ks * 4 + (lane >> 4);
            #pragma unroll
            for (int m = 0; m < 4; ++m) {
                int row = wr * 64 + m * 16 + (lane & 15);
                af[m] = *(const bf16x8*)&As[b][row * 64 + ((sl ^ (row & 7)) * 8)];
            }
            #pragma unroll
            for (int n = 0; n < 4; ++n) {
                int row = wc * 64 + n * 16 + (lane & 15);
                bfr[n] = *(const bf16x8*)&Bs[b][row * 64 + ((sl ^ (row & 7)) * 8)];
            }
            #pragma unroll
            for (int m = 0; m < 4; ++m)
                #pragma unroll
                for (int n = 0; n < 4; ++n)
                    acc[m][n] = __builtin_amdgcn_mfma_f32_16x16x32_bf16(af[m], bfr[n], acc[m][n], 0, 0, 0);
        }
    };

    STAGE(0, 0);                                   // prologue: tile 0 in flight
    #pragma unroll
    for (int t = 0; t < 4; ++t) {
        if (t < 3) {
            STAGE((t + 1) & 1, (t + 1) * 64);      // tile t+1 in flight (8 loads)
            asm volatile("s_waitcnt vmcnt(8)" ::: "memory");   // tile t done
        } else {
            asm volatile("s_waitcnt vmcnt(0)" ::: "memory");
        }
        __builtin_amdgcn_s_barrier();              // all waves: tile t ready
        __builtin_amdgcn_sched_barrier(0);
        COMPUTE(t & 1);
        __builtin_amdgcn_s_barrier();              // done reading buf before overwrite
    }

    bool toY = by < 2;
    int cBase = (by & 1) * 128 + wc * 64;
    #pragma unroll
    for (int m = 0; m < 4; ++m) {
        int gm0 = mBase + wr * 64 + m * 16 + (lane >> 4) * 4;
        #pragma unroll
        for (int n = 0; n < 4; ++n) {
            int gn = cBase + n * 16 + (lane & 15);
            f32x4 v = acc[m][n];
            #pragma unroll
            for (int j = 0; j < 4; ++j) {
                int gm = gm0 + j;
                if (gm < N_NODES) {
                    if (toY) Y[(size_t)gm * 256 + gn] = f2bf(v[j]);
                    else     Z[(size_t)gm * 256 + gn] = v[j];
                }
            }
        }
    }
}

// ---------------------------------------------------------------------------
// Aggregation (EXACT round-7 hot loop: wave = one (node,dir) stream, NPW=2,
// 16B gathers, 4 edges/load, 4 loads in flight, unconditional __shfl +
// predicated load) + BN-stat epilogue: per-lane s1/s2 of the 2 columns this
// lane writes -> LDS half-pair reduce -> atomics into stats copy blockIdx&7
// (caps per-address atomic chains at 5000/8=625; removes the bn_stats pass).
// ---------------------------------------------------------------------------
#define NPW 2
__global__ __launch_bounds__(256) void aggregate_stats_kernel(
    const unsigned short* __restrict__ Y,
    const int* __restrict__ offF, const int* __restrict__ listF,
    const int* __restrict__ offB, const int* __restrict__ listB,
    float* __restrict__ H, float* __restrict__ stats)
{
    int tid = threadIdx.x, lane = tid & 63, wave = tid >> 6;
    int dir = wave >> 1, half = wave & 1;
    const int* off  = dir ? offB : offF;
    const int* list = dir ? listB : listF;
    int eg = lane >> 4;        // which edge of the group of 4
    int c16 = lane & 15;       // 16B column slot within the row
    int nodeBase = blockIdx.x * (2 * NPW) + half * NPW;

    float s1a = 0.f, s1b = 0.f, s2a = 0.f, s2b = 0.f;

    for (int jn = 0; jn < NPW; ++jn) {
        int n = nodeBase + jn;                 // grid exact: always < N_NODES
        int beg = off[n], end = off[n + 1];
        int deg = end - beg;
        float acc[8] = {0.f, 0.f, 0.f, 0.f, 0.f, 0.f, 0.f, 0.f};

        for (int i = beg; i < end; i += 64) {
            int c = end - i; if (c > 64) c = 64;
            int u_l = list[i + (lane < c ? lane : 0)];
            for (int e0 = 0; e0 < c; e0 += 16) {
                uint4 v[4];
                #pragma unroll
                for (int k = 0; k < 4; ++k) {
                    int ei = e0 + k * 4 + eg;
                    // shfl with ALL lanes active (clamped index), then
                    // predicate only the memory access:
                    int u = __shfl(u_l, ei < c ? ei : 0);
                    v[k] = make_uint4(0u, 0u, 0u, 0u);
                    if (ei < c)
                        v[k] = *(const uint4*)(Y + (size_t)u * 256 + dir * 128 + c16 * 8);
                }
                #pragma unroll
                for (int k = 0; k < 4; ++k) {
                    acc[0] += bflo(v[k].x); acc[1] += bfhi(v[k].x);
                    acc[2] += bflo(v[k].y); acc[3] += bfhi(v[k].y);
                    acc[4] += bflo(v[k].z); acc[5] += bfhi(v[k].z);
                    acc[6] += bflo(v[k].w); acc[7] += bfhi(v[k].w);
                }
            }
        }
        #pragma unroll
        for (int j = 0; j < 8; ++j) {
            acc[j] += __shfl_xor(acc[j], 16);
            acc[j] += __shfl_xor(acc[j], 32);
        }
        // static-index select of this lane's two columns (rule #20)
        float h0 = (eg & 2) ? ((eg & 1) ? acc[6] : acc[4]) : ((eg & 1) ? acc[2] : acc[0]);
        float h1 = (eg & 2) ? ((eg & 1) ? acc[7] : acc[5]) : ((eg & 1) ? acc[3] : acc[1]);
        float inv = 1.f / fmaxf((float)deg, 1.f);
        float2* hp = (float2*)(H + (size_t)n * 256 + dir * 128 + c16 * 8 + eg * 2);
        float2 z = *hp;
        float v0 = fmaf(h0, inv, z.x);
        float v1 = fmaf(h1, inv, z.y);
        *hp = make_float2(v0, v1);
        s1a += v0; s2a += v0 * v0;
        s1b += v1; s2b += v1 * v1;
    }

    // BN partials: pair-reduce across the two half-waves of each dir, then
    // 4 atomics per lane of the half0 waves (512 atomics/block total).
    __shared__ float red[2][64][4];
    if (half) {
        red[dir][lane][0] = s1a; red[dir][lane][1] = s1b;
        red[dir][lane][2] = s2a; red[dir][lane][3] = s2b;
    }
    __syncthreads();
    if (!half) {
        s1a += red[dir][lane][0]; s1b += red[dir][lane][1];
        s2a += red[dir][lane][2]; s2b += red[dir][lane][3];
        int col = dir * 128 + c16 * 8 + eg * 2;
        float* st = stats + (blockIdx.x & (NSTATS - 1)) * 512;
        atomicAdd(&st[col], s1a);
        atomicAdd(&st[col + 1], s1b);
        atomicAdd(&st[256 + col], s2a);
        atomicAdd(&st[256 + col + 1], s2b);
    }
}

// ---------------------------------------------------------------------------
// BatchNorm finalize + ReLU, in place on d_out (sums the NSTATS stat copies).
// ---------------------------------------------------------------------------
__global__ __launch_bounds__(256) void bn_kernel(
    const float* __restrict__ stats, const float* __restrict__ gamma,
    const float* __restrict__ beta, float* __restrict__ H)
{
    __shared__ float sc[256], sf[256];
    int tid = threadIdx.x;
    {
        float s1 = 0.f, s2 = 0.f;
        #pragma unroll
        for (int c = 0; c < NSTATS; ++c) {
            s1 += stats[c * 512 + tid];
            s2 += stats[c * 512 + 256 + tid];
        }
        float mean = s1 * (1.f / N_NODES);
        float var  = s2 * (1.f / N_NODES) - mean * mean;
        float s = rsqrtf(fmaxf(var, 0.f) + BN_EPS) * gamma[tid];
        sc[tid] = s;
        sf[tid] = beta[tid] - mean * s;
    }
    __syncthreads();
    for (int n = blockIdx.x; n < N_NODES; n += gridDim.x) {
        size_t idx = (size_t)n * 256 + tid;
        float h = H[idx];
        H[idx] = fmaxf(h * sc[tid] + sf[tid], 0.f);
    }
}

// ---------------------------------------------------------------------------
extern "C" void kernel_launch(void* const* d_in, const int* in_sizes, int n_in,
                              void* d_out, int out_size, void* d_ws, size_t ws_size,
                              hipStream_t stream) {
    const float* x     = (const float*)d_in[0];
    const int*   edge  = (const int*)d_in[1];   // [2][N_EDGES]
    const float* Wlf   = (const float*)d_in[2];
    // d_in[3] = b_l_f : cancels under BatchNorm (per-column shift) - unused
    const float* Wrf   = (const float*)d_in[4];
    const float* Wlb   = (const float*)d_in[5];
    // d_in[6] = b_l_b : unused (cancels)
    const float* Wrb   = (const float*)d_in[7];
    const float* gamma = (const float*)d_in[8];
    const float* beta  = (const float*)d_in[9];
    float* out = (float*)d_out;

    const int* src = edge;
    const int* dst = edge + N_EDGES;

    char* ws = (char*)d_ws;
    size_t off = 0;
    auto alloc = [&](size_t bytes) { size_t r = off; off += (bytes + 255) & ~(size_t)255; return r; };
    unsigned short* Y  = (unsigned short*)(ws + alloc((size_t)N_NODES * 256 * 2)); // 10.24 MB
    unsigned short* Xb = (unsigned short*)(ws + alloc((size_t)N_NODES * 256 * 2)); // 10.24 MB
    unsigned short* Wb = (unsigned short*)(ws + alloc((size_t)4 * 128 * 256 * 2)); // 256 KB
    int* offF  = (int*)(ws + alloc((size_t)(N_NODES + 1) * 4));
    int* offB  = (int*)(ws + alloc((size_t)(N_NODES + 1) * 4));
    int* listF = (int*)(ws + alloc((size_t)N_EDGES * 4));
    int* listB = (int*)(ws + alloc((size_t)N_EDGES * 4));
    unsigned int* rank2 = (unsigned int*)(ws + alloc((size_t)N_EDGES * 4));        // 1.28 MB
    size_t zbase_off = off;
    int* cntF = (int*)(ws + alloc((size_t)N_NODES * 4));
    int* cntB = (int*)(ws + alloc((size_t)N_NODES * 4));
    float* stats = (float*)(ws + alloc((size_t)NSTATS * 512 * 4));                 // 16 KB
    size_t zbytes = off - zbase_off;          // 256B-aligned => multiple of 16
    int zquads = (int)(zbytes / 16);

    zero_kernel<<<(zquads + 255) / 256, 256, 0, stream>>>((uint4*)(ws + zbase_off), zquads);

    cvt_count_kernel<<<CVTB2 + CNT256, 256, 0, stream>>>(
        x, Wlf, Wlb, Wrf, Wrb, Xb, Wb, src, dst, cntF, cntB, rank2);

    scan_kernel<<<2, 1024, 0, stream>>>(cntF, offF, cntB, offB);

    gemm_fill_kernel<<<NGEMM + FILLB, 256, 0, stream>>>(
        src, dst, offF, offB, rank2, listF, listB, Xb, Wb, Y, out);

    aggregate_stats_kernel<<<N_NODES / (2 * NPW), 256, 0, stream>>>(
        Y, offF, listF, offB, listB, out, stats);

    bn_kernel<<<2048, 256, 0, stream>>>(stats, gamma, beta, out);
}